// Round 5
// baseline (2380.408 us; speedup 1.0000x reference)
//
#include <hip/hip_runtime.h>

typedef unsigned short u16;
typedef unsigned int u32;

#define NPTS 131072
#define CD 128
#define KOFF 27
#define MMAP 65536
#define LDAB 136   // LDS row stride (u16) for A/B tiles: 128+8
#define LDC 132    // LDS row stride (u16) for C repack: keeps store banks <=2-way

__device__ __forceinline__ u16 f2bf(float f) {  // f32 -> bf16 RNE
  u32 u = __float_as_uint(f);
  u32 r = (u + 0x7fffu + ((u >> 16) & 1u)) >> 16;
  return (u16)r;
}

typedef __attribute__((ext_vector_type(8))) short bf16x8;
typedef __attribute__((ext_vector_type(4))) float f32x4;

// ---------------- dtype conversion ----------------
__global__ __launch_bounds__(256) void k_convert_x(const float* __restrict__ x,
                                                   u16* __restrict__ xb) {
  long i = ((long)blockIdx.x * 256 + threadIdx.x) * 8;
  float4 a = *(const float4*)(x + i);
  float4 b = *(const float4*)(x + i + 4);
  uint4 v;
  v.x = f2bf(a.x) | ((u32)f2bf(a.y) << 16);
  v.y = f2bf(a.z) | ((u32)f2bf(a.w) << 16);
  v.z = f2bf(b.x) | ((u32)f2bf(b.y) << 16);
  v.w = f2bf(b.z) | ((u32)f2bf(b.w) << 16);
  *(uint4*)(xb + i) = v;
}

// W [K][ci][co] f32 -> Wb [K][co][ci] bf16
__global__ __launch_bounds__(256) void k_convert_w(const float* __restrict__ W,
                                                   u16* __restrict__ Wb) {
  int idx = blockIdx.x * 256 + threadIdx.x;
  if (idx >= KOFF * 2048) return;
  int k = idx >> 11;
  int rem = idx & 2047;
  int co = rem >> 4;
  int cc = rem & 15;
  const float* ws = W + (long)k * (CD * CD) + (long)(cc * 8) * CD + co;
  u16 t[8];
#pragma unroll
  for (int j = 0; j < 8; ++j) t[j] = f2bf(ws[j * CD]);
  uint4 v;
  v.x = t[0] | ((u32)t[1] << 16);
  v.y = t[2] | ((u32)t[3] << 16);
  v.z = t[4] | ((u32)t[5] << 16);
  v.w = t[6] | ((u32)t[7] << 16);
  ((uint4*)Wb)[idx] = v;
}

// ---------------- batched counting sort: all P passes of one conv in one set ----------------
// bins are pass-segmented: hist[p*NPTS + row]; offs has per-pass stride NPTS+1.
__global__ __launch_bounds__(256) void k_hist2(const int* __restrict__ mo,
                                               u32* __restrict__ hist, int bpp) {
  int p = blockIdx.x / bpp;
  int i = blockIdx.x * 256 + threadIdx.x;
  atomicAdd(&hist[(size_t)p * NPTS + mo[i]], 1u);
}

__global__ __launch_bounds__(256) void k_scanA2(const u32* __restrict__ hist,
                                                u32* __restrict__ offs,
                                                u32* __restrict__ bsum) {
  __shared__ u32 sh[256];
  int t = threadIdx.x, b = blockIdx.x;
  int p = b >> 9, rblk = b & 511;
  u32 v = hist[(size_t)p * NPTS + rblk * 256 + t];
  u32 run = v;
  sh[t] = run;
  __syncthreads();
  for (int d = 1; d < 256; d <<= 1) {
    u32 y = (t >= d) ? sh[t - d] : 0u;
    __syncthreads();
    run += y;
    sh[t] = run;
    __syncthreads();
  }
  offs[(size_t)p * (NPTS + 1) + rblk * 256 + t] = run - v;
  if (t == 255) bsum[b] = run;
}

__global__ __launch_bounds__(512) void k_scanB2(u32* __restrict__ bsum) {
  __shared__ u32 sh[512];
  int t = threadIdx.x;
  u32* bp = bsum + blockIdx.x * 512;
  u32 v = bp[t];
  u32 run = v;
  sh[t] = run;
  __syncthreads();
  for (int d = 1; d < 512; d <<= 1) {
    u32 y = (t >= d) ? sh[t - d] : 0u;
    __syncthreads();
    run += y;
    sh[t] = run;
    __syncthreads();
  }
  bp[t] = run - v;
}

__global__ __launch_bounds__(256) void k_scanC2(u32* __restrict__ offs,
                                                const u32* __restrict__ bsum, int kcnt) {
  int t = threadIdx.x, b = blockIdx.x;
  int p = b >> 9, rblk = b & 511;
  size_t base = (size_t)p * (NPTS + 1);
  offs[base + rblk * 256 + t] += bsum[b];
  if (rblk == 0 && t == 0) {
    int kc = KOFF - p * kcnt;
    if (kc > kcnt) kc = kcnt;
    offs[base + NPTS] = (u32)kc * MMAP;
  }
}

// rank + sorted-row-key array: srt[pass_base + rank] = output row of that contrib slot
__global__ __launch_bounds__(256) void k_rank2(const int* __restrict__ mo,
                                               const u32* __restrict__ offs,
                                               u32* __restrict__ cur,
                                               u32* __restrict__ rank,
                                               u32* __restrict__ srt, int bpp) {
  int p = blockIdx.x / bpp;
  int i = blockIdx.x * 256 + threadIdx.x;
  int o = mo[i];
  u32 r = offs[(size_t)p * (NPTS + 1) + o] + atomicAdd(&cur[(size_t)p * NPTS + o], 1u);
  rank[i] = r;
  srt[(size_t)p * bpp * 256 + r] = (u32)o;
}

// ---------------- gather-GEMM, natural (k, m-tile) order, rank-scatter rows ----------------
__global__ __launch_bounds__(256) void k_gemm3(const u16* __restrict__ src,
                                               const u16* __restrict__ Wb,
                                               const int* __restrict__ mi,   // pass base
                                               const u32* __restrict__ rank, // pass base
                                               u16* __restrict__ contrib,
                                               int kbase) {
  __shared__ u16 As[64 * LDAB];
  __shared__ u16 Bs[128 * LDAB];
  __shared__ u32 sin[64];
  __shared__ u32 srow[64];
  const int t = threadIdx.x;
  const int b = blockIdx.x;
  const int klocal = b >> 10;
  const int i0 = klocal * MMAP + (b & 1023) * 64;

  if (t < 64) {
    sin[t] = (u32)mi[i0 + t];
    srow[t] = rank[i0 + t];
  }
  const uint4* wsrc = (const uint4*)(Wb + (long)(kbase + klocal) * (CD * CD));
#pragma unroll
  for (int i = 0; i < 8; ++i) {
    int q = i * 256 + t;
    int co = q >> 4, cc = q & 15;
    *(uint4*)&Bs[co * LDAB + cc * 8] = wsrc[q];
  }
  __syncthreads();
#pragma unroll
  for (int i = 0; i < 4; ++i) {
    int q = i * 256 + t;
    int r = q >> 4, cc = q & 15;
    long row = sin[r];
    *(uint4*)&As[r * LDAB + cc * 8] = ((const uint4*)(src + row * CD))[cc];
  }
  __syncthreads();

  const int wave = t >> 6, lane = t & 63;
  const int lr = lane & 15, quad = lane >> 4;
  const int wm = (wave & 1) * 32;
  const int wn = (wave >> 1) * 64;
  f32x4 acc[2][4] = {};
#pragma unroll
  for (int kk = 0; kk < 4; ++kk) {
    bf16x8 a[2], bfr[4];
#pragma unroll
    for (int mt = 0; mt < 2; ++mt)
      a[mt] = *(const bf16x8*)&As[(wm + mt * 16 + lr) * LDAB + (kk * 4 + quad) * 8];
#pragma unroll
    for (int nt = 0; nt < 4; ++nt)
      bfr[nt] = *(const bf16x8*)&Bs[(wn + nt * 16 + lr) * LDAB + (kk * 4 + quad) * 8];
#pragma unroll
    for (int mt = 0; mt < 2; ++mt)
#pragma unroll
      for (int nt = 0; nt < 4; ++nt)
        acc[mt][nt] = __builtin_amdgcn_mfma_f32_16x16x32_bf16(a[mt], bfr[nt], acc[mt][nt], 0, 0, 0);
  }

  // repack C through LDS (C/D layout: col = lane&15, row = quad*4+reg), then coalesced row stores
  __syncthreads();
  u16* Cs = As;  // reuse: 64*132 u16 = 16.9KB <= As 17.4KB
#pragma unroll
  for (int mt = 0; mt < 2; ++mt)
#pragma unroll
    for (int v = 0; v < 4; ++v) {
      int slot = wm + mt * 16 + quad * 4 + v;
#pragma unroll
      for (int nt = 0; nt < 4; ++nt)
        Cs[slot * LDC + wn + nt * 16 + lr] = f2bf(acc[mt][nt][v]);
    }
  __syncthreads();
#pragma unroll
  for (int i = 0; i < 4; ++i) {
    int q = i * 256 + t;
    int r = q >> 4, cc = q & 15;
    size_t rk = srow[r];
    *(uint4*)(contrib + rk * CD + cc * 8) = *(const uint4*)&Cs[r * LDC + cc * 8];
  }
}

// ---------------- segmented reduce v6: entry-parallel streaming run-merge ----------------
// Wave owns 64 CONSECUTIVE contrib entries (16KB contiguous); quad owns 16 consecutive entries.
// In-lane run-merge keyed by srt[]; interior runs -> plain coalesced 512B acc RMW (race-free:
// all entries of that row lie inside the quad); quad-boundary runs -> f32 atomicAdd (~2/quad).
// acc must be pre-zeroed; no first/last special cases.
__global__ __launch_bounds__(256, 4) void k_segreduce6(const u16* __restrict__ contrib,
                                                       const u32* __restrict__ srt,
                                                       float* __restrict__ acc,
                                                       u32 total) {
  const int wave = threadIdx.x >> 6, lane = threadIdx.x & 63;
  const u32 e_base = (blockIdx.x * 4 + wave) * 64;
  const int q = lane >> 4, sub = lane & 15;

  u32 kk = srt[e_base + lane];  // 64 sorted row keys, one per lane
  u32 prevk = (q == 0) ? ((e_base == 0) ? 0xFFFFFFFFu : srt[e_base - 1])
                       : __shfl(kk, 16 * q - 1);
  u32 nextk = (q == 3) ? ((e_base + 64 >= total) ? 0xFFFFFFFFu : srt[e_base + 64])
                       : __shfl(kk, 16 * q + 16);

  // 16 independent value loads (quad's 16 consecutive entries, 256B each)
  uint4 d[16];
#pragma unroll
  for (int i = 0; i < 16; ++i)
    d[i] = *(const uint4*)(contrib + (size_t)(e_base + 16 * q + i) * CD + sub * 8);

  float run[8];
  auto set8 = [&](uint4 dd) {
    run[0] = __uint_as_float(dd.x << 16);
    run[1] = __uint_as_float(dd.x & 0xffff0000u);
    run[2] = __uint_as_float(dd.y << 16);
    run[3] = __uint_as_float(dd.y & 0xffff0000u);
    run[4] = __uint_as_float(dd.z << 16);
    run[5] = __uint_as_float(dd.z & 0xffff0000u);
    run[6] = __uint_as_float(dd.w << 16);
    run[7] = __uint_as_float(dd.w & 0xffff0000u);
  };
  auto add8 = [&](uint4 dd) {
    run[0] += __uint_as_float(dd.x << 16);
    run[1] += __uint_as_float(dd.x & 0xffff0000u);
    run[2] += __uint_as_float(dd.y << 16);
    run[3] += __uint_as_float(dd.y & 0xffff0000u);
    run[4] += __uint_as_float(dd.z << 16);
    run[5] += __uint_as_float(dd.z & 0xffff0000u);
    run[6] += __uint_as_float(dd.w << 16);
    run[7] += __uint_as_float(dd.w & 0xffff0000u);
  };
  auto emit = [&](u32 row, bool at) {
    float* ap = acc + (size_t)row * CD + sub * 8;
    if (at) {
#pragma unroll
      for (int j = 0; j < 8; ++j) atomicAdd(ap + j, run[j]);
    } else {
      float4 p0 = *(float4*)ap;
      float4 p1 = *(float4*)(ap + 4);
      p0.x += run[0]; p0.y += run[1]; p0.z += run[2]; p0.w += run[3];
      p1.x += run[4]; p1.y += run[5]; p1.z += run[6]; p1.w += run[7];
      *(float4*)ap = p0;
      *(float4*)(ap + 4) = p1;
    }
  };

  u32 curk = __shfl(kk, 16 * q);
  set8(d[0]);
  bool firstRun = true;
#pragma unroll
  for (int i = 1; i < 16; ++i) {
    u32 ki = __shfl(kk, 16 * q + i);
    if (ki == curk) {
      add8(d[i]);
    } else {
      emit(curk, firstRun && (curk == prevk));
      curk = ki;
      set8(d[i]);
      firstRun = false;
    }
  }
  emit(curk, (curk == nextk) || (firstRun && (curk == prevk)));
}

// ---------------- per-channel BN stats over acc (sum, sumsq) ----------------
__global__ __launch_bounds__(256) void k_stats(const float* __restrict__ acc,
                                               float* __restrict__ stats) {
  const int t = threadIdx.x;
  const long total = (long)NPTS * CD / 4;
  const long stride = (long)gridDim.x * 256;
  long idx = (long)blockIdx.x * 256 + t;
  float s0 = 0.f, s1 = 0.f, s2 = 0.f, s3 = 0.f;
  float q0 = 0.f, q1 = 0.f, q2 = 0.f, q3 = 0.f;
  for (long i = idx; i < total; i += stride) {
    float4 a = *(const float4*)(acc + i * 4);
    s0 += a.x; q0 += a.x * a.x;
    s1 += a.y; q1 += a.y * a.y;
    s2 += a.z; q2 += a.z * a.z;
    s3 += a.w; q3 += a.w * a.w;
  }
  __shared__ float sh[2048];
  sh[t * 8 + 0] = s0; sh[t * 8 + 1] = s1; sh[t * 8 + 2] = s2; sh[t * 8 + 3] = s3;
  sh[t * 8 + 4] = q0; sh[t * 8 + 5] = q1; sh[t * 8 + 6] = q2; sh[t * 8 + 7] = q3;
  __syncthreads();
  if (t < 32) {
#pragma unroll
    for (int j = 0; j < 4; ++j) {
      float a = 0.f, qq = 0.f;
#pragma unroll
      for (int g = 0; g < 8; ++g) {
        a += sh[(t + g * 32) * 8 + j];
        qq += sh[(t + g * 32) * 8 + 4 + j];
      }
      atomicAdd(&stats[t * 4 + j], a);
      atomicAdd(&stats[128 + t * 4 + j], qq);
    }
  }
}

// ---------------- BN finalize / apply ----------------
__global__ void k_finalize(const float* __restrict__ stats, const float* __restrict__ gamma,
                           const float* __restrict__ beta, float* __restrict__ scsh) {
  int c = threadIdx.x;
  float mean = stats[c] * (1.f / NPTS);
  float var = stats[128 + c] * (1.f / NPTS) - mean * mean;
  float sc = rsqrtf(var + 1e-5f) * gamma[c];
  scsh[c] = sc;
  scsh[128 + c] = beta[c] - mean * sc;
}

__device__ __forceinline__ float elu(float v) { return v > 0.f ? v : expf(v) - 1.f; }

// reads acc, writes bf16 mid activations, and re-zeros acc for conv2
__global__ __launch_bounds__(256) void k_apply_mid(float* __restrict__ acc,
                                                   const float* __restrict__ scsh,
                                                   u16* __restrict__ y) {
  long i = ((long)blockIdx.x * 256 + threadIdx.x) * 4;
  int c = (int)(i & 127);
  float4 a = *(const float4*)(acc + i);
  float r0 = elu(a.x * scsh[c] + scsh[128 + c]);
  float r1 = elu(a.y * scsh[c + 1] + scsh[129 + c]);
  float r2 = elu(a.z * scsh[c + 2] + scsh[130 + c]);
  float r3 = elu(a.w * scsh[c + 3] + scsh[131 + c]);
  uint2 v;
  v.x = f2bf(r0) | ((u32)f2bf(r1) << 16);
  v.y = f2bf(r2) | ((u32)f2bf(r3) << 16);
  *(uint2*)(y + i) = v;
  *(float4*)(acc + i) = make_float4(0.f, 0.f, 0.f, 0.f);
}

__global__ __launch_bounds__(256) void k_apply_final(const float* __restrict__ acc,
                                                     const float* __restrict__ scsh,
                                                     const float* __restrict__ x,
                                                     float* __restrict__ out) {
  long i = ((long)blockIdx.x * 256 + threadIdx.x) * 4;
  int c = (int)(i & 127);
  float4 a = *(const float4*)(acc + i);
  float4 rx = *(const float4*)(x + i);
  float4 o;
  o.x = elu(a.x * scsh[c] + scsh[128 + c] + rx.x);
  o.y = elu(a.y * scsh[c + 1] + scsh[129 + c] + rx.y);
  o.z = elu(a.z * scsh[c + 2] + scsh[130 + c] + rx.z);
  o.w = elu(a.w * scsh[c + 3] + scsh[131 + c] + rx.w);
  *(float4*)(out + i) = o;
}

// ---------------- host ----------------
extern "C" void kernel_launch(void* const* d_in, const int* in_sizes, int n_in,
                              void* d_out, int out_size, void* d_ws, size_t ws_size,
                              hipStream_t stream) {
  const float* x = (const float*)d_in[0];
  const float* W1 = (const float*)d_in[1];
  const float* g1 = (const float*)d_in[2];
  const float* b1 = (const float*)d_in[3];
  const float* W2 = (const float*)d_in[4];
  const float* g2 = (const float*)d_in[5];
  const float* b2 = (const float*)d_in[6];
  const int* m1i = (const int*)d_in[7];
  const int* m1o = (const int*)d_in[8];
  const int* m2i = (const int*)d_in[9];
  const int* m2o = (const int*)d_in[10];
  float* out = (float*)d_out;

  char* base = (char*)d_ws;
  size_t off = 0;
  auto alloc = [&](size_t bytes) -> void* {
    void* r = base + off;
    off = (off + bytes + 255) & ~(size_t)255;
    return r;
  };
  // xb doubles as the mid-activation buffer (xb dead after conv1's last gemm pass).
  u16* xb = (u16*)alloc((size_t)NPTS * CD * 2);
  u16* Wb1 = (u16*)alloc((size_t)KOFF * CD * CD * 2);
  u16* Wb2 = (u16*)alloc((size_t)KOFF * CD * CD * 2);
  float* acc = (float*)alloc((size_t)NPTS * CD * 4);
  float* stats = (float*)alloc(256 * 4);
  float* scsh = (float*)alloc(256 * 4);

  // choose kcnt (k-offsets per pass) so contrib + pass-segmented sort buffers fit
  int kcnt = 1, P = KOFF;
  for (int kc = KOFF; kc >= 1; --kc) {
    int Pp = (KOFF + kc - 1) / kc;
    size_t need = off + 2 * (size_t)Pp * NPTS * 4 + 512         // hist+cur
                  + (size_t)Pp * (NPTS + 1) * 4 + 256           // offs
                  + (size_t)Pp * 512 * 4 + 256                  // bsum
                  + (size_t)KOFF * MMAP * 4 + 256               // rank
                  + (size_t)Pp * kc * MMAP * 4 + 256            // srt (sorted row keys)
                  + (size_t)kc * MMAP * CD * 2 + 4096;          // contrib
    if (need <= ws_size) {
      kcnt = kc;
      P = Pp;
      break;
    }
  }
  u32* hist = (u32*)alloc((size_t)P * NPTS * 4);
  u32* cur = (u32*)alloc((size_t)P * NPTS * 4);  // contiguous with hist for one memset
  u32* offs = (u32*)alloc((size_t)P * (NPTS + 1) * 4);
  u32* bsum = (u32*)alloc((size_t)P * 512 * 4);
  u32* rank = (u32*)alloc((size_t)KOFF * MMAP * 4);
  u32* srt = (u32*)alloc((size_t)P * kcnt * MMAP * 4);
  u16* contrib = (u16*)alloc((size_t)kcnt * MMAP * CD * 2);

  hipMemsetAsync(acc, 0, (size_t)NPTS * CD * 4, stream);  // apply_mid re-zeros for conv2
  k_convert_x<<<(NPTS * CD) / 2048, 256, 0, stream>>>(x, xb);
  k_convert_w<<<(KOFF * 2048 + 255) / 256, 256, 0, stream>>>(W1, Wb1);
  k_convert_w<<<(KOFF * 2048 + 255) / 256, 256, 0, stream>>>(W2, Wb2);

  const int nb = (KOFF * MMAP) / 256;       // hist/rank grid
  const int bpp = kcnt * (MMAP / 256);      // blocks per pass

  auto run_conv = [&](const u16* srcm, const u16* Wbm, const int* mi, const int* mo) {
    hipMemsetAsync(stats, 0, 1024, stream);
    hipMemsetAsync(hist, 0, 2 * (size_t)P * NPTS * 4, stream);
    k_hist2<<<nb, 256, 0, stream>>>(mo, hist, bpp);
    k_scanA2<<<512 * P, 256, 0, stream>>>(hist, offs, bsum);
    k_scanB2<<<P, 512, 0, stream>>>(bsum);
    k_scanC2<<<512 * P, 256, 0, stream>>>(offs, bsum, kcnt);
    k_rank2<<<nb, 256, 0, stream>>>(mo, offs, cur, rank, srt, bpp);
    for (int p = 0; p < P; ++p) {
      int kc = (KOFF - p * kcnt < kcnt) ? KOFF - p * kcnt : kcnt;
      k_gemm3<<<kc * 1024, 256, 0, stream>>>(srcm, Wbm, mi + (long)p * kcnt * MMAP,
                                             rank + (long)p * kcnt * MMAP, contrib, p * kcnt);
      k_segreduce6<<<kc * 256, 256, 0, stream>>>(contrib, srt + (size_t)p * kcnt * MMAP, acc,
                                                 (u32)kc * MMAP);
    }
    k_stats<<<2048, 256, 0, stream>>>(acc, stats);
  };

  run_conv(xb, Wb1, m1i, m1o);
  k_finalize<<<1, 128, 0, stream>>>(stats, g1, b1, scsh);
  k_apply_mid<<<(NPTS * CD) / 1024, 256, 0, stream>>>(acc, scsh, xb);

  run_conv(xb, Wb2, m2i, m2o);
  k_finalize<<<1, 128, 0, stream>>>(stats, g2, b2, scsh);
  k_apply_final<<<(NPTS * CD) / 1024, 256, 0, stream>>>(acc, scsh, x, out);
}

// Round 6
// 1219.318 us; speedup vs baseline: 1.9522x; 1.9522x over previous
//
#include <hip/hip_runtime.h>

typedef unsigned short u16;
typedef unsigned int u32;

#define NPTS 131072
#define CD 128
#define KOFF 27
#define MMAP 65536
#define LDAB 136   // LDS row stride (u16) for A/B tiles: 128+8
#define LDC 132    // LDS row stride (u16) for C repack: keeps store banks <=2-way

__device__ __forceinline__ u16 f2bf(float f) {  // f32 -> bf16 RNE
  u32 u = __float_as_uint(f);
  u32 r = (u + 0x7fffu + ((u >> 16) & 1u)) >> 16;
  return (u16)r;
}

__device__ __forceinline__ float bfLO(u32 u) { return __uint_as_float(u << 16); }
__device__ __forceinline__ float bfHI(u32 u) { return __uint_as_float(u & 0xffff0000u); }

typedef __attribute__((ext_vector_type(8))) short bf16x8;
typedef __attribute__((ext_vector_type(4))) float f32x4;

// ---------------- dtype conversion ----------------
__global__ __launch_bounds__(256) void k_convert_x(const float* __restrict__ x,
                                                   u16* __restrict__ xb) {
  long i = ((long)blockIdx.x * 256 + threadIdx.x) * 8;
  float4 a = *(const float4*)(x + i);
  float4 b = *(const float4*)(x + i + 4);
  uint4 v;
  v.x = f2bf(a.x) | ((u32)f2bf(a.y) << 16);
  v.y = f2bf(a.z) | ((u32)f2bf(a.w) << 16);
  v.z = f2bf(b.x) | ((u32)f2bf(b.y) << 16);
  v.w = f2bf(b.z) | ((u32)f2bf(b.w) << 16);
  *(uint4*)(xb + i) = v;
}

// W [K][ci][co] f32 -> Wb [K][co][ci] bf16
__global__ __launch_bounds__(256) void k_convert_w(const float* __restrict__ W,
                                                   u16* __restrict__ Wb) {
  int idx = blockIdx.x * 256 + threadIdx.x;
  if (idx >= KOFF * 2048) return;
  int k = idx >> 11;
  int rem = idx & 2047;
  int co = rem >> 4;
  int cc = rem & 15;
  const float* ws = W + (long)k * (CD * CD) + (long)(cc * 8) * CD + co;
  u16 t[8];
#pragma unroll
  for (int j = 0; j < 8; ++j) t[j] = f2bf(ws[j * CD]);
  uint4 v;
  v.x = t[0] | ((u32)t[1] << 16);
  v.y = t[2] | ((u32)t[3] << 16);
  v.z = t[4] | ((u32)t[5] << 16);
  v.w = t[6] | ((u32)t[7] << 16);
  ((uint4*)Wb)[idx] = v;
}

// ---------------- batched counting sort: all P passes of one conv in one set ----------------
// bins are pass-segmented: hist[p*NPTS + row]; offs has per-pass stride NPTS+1.
__global__ __launch_bounds__(256) void k_hist2(const int* __restrict__ mo,
                                               u32* __restrict__ hist, int bpp) {
  int p = blockIdx.x / bpp;
  int i = blockIdx.x * 256 + threadIdx.x;
  atomicAdd(&hist[(size_t)p * NPTS + mo[i]], 1u);
}

__global__ __launch_bounds__(256) void k_scanA2(const u32* __restrict__ hist,
                                                u32* __restrict__ offs,
                                                u32* __restrict__ bsum) {
  __shared__ u32 sh[256];
  int t = threadIdx.x, b = blockIdx.x;
  int p = b >> 9, rblk = b & 511;
  u32 v = hist[(size_t)p * NPTS + rblk * 256 + t];
  u32 run = v;
  sh[t] = run;
  __syncthreads();
  for (int d = 1; d < 256; d <<= 1) {
    u32 y = (t >= d) ? sh[t - d] : 0u;
    __syncthreads();
    run += y;
    sh[t] = run;
    __syncthreads();
  }
  offs[(size_t)p * (NPTS + 1) + rblk * 256 + t] = run - v;
  if (t == 255) bsum[b] = run;
}

__global__ __launch_bounds__(512) void k_scanB2(u32* __restrict__ bsum) {
  __shared__ u32 sh[512];
  int t = threadIdx.x;
  u32* bp = bsum + blockIdx.x * 512;
  u32 v = bp[t];
  u32 run = v;
  sh[t] = run;
  __syncthreads();
  for (int d = 1; d < 512; d <<= 1) {
    u32 y = (t >= d) ? sh[t - d] : 0u;
    __syncthreads();
    run += y;
    sh[t] = run;
    __syncthreads();
  }
  bp[t] = run - v;
}

__global__ __launch_bounds__(256) void k_scanC2(u32* __restrict__ offs,
                                                const u32* __restrict__ bsum, int kcnt) {
  int t = threadIdx.x, b = blockIdx.x;
  int p = b >> 9, rblk = b & 511;
  size_t base = (size_t)p * (NPTS + 1);
  offs[base + rblk * 256 + t] += bsum[b];
  if (rblk == 0 && t == 0) {
    int kc = KOFF - p * kcnt;
    if (kc > kcnt) kc = kcnt;
    offs[base + NPTS] = (u32)kc * MMAP;
  }
}

__global__ __launch_bounds__(256) void k_rank2(const int* __restrict__ mo,
                                               const u32* __restrict__ offs,
                                               u32* __restrict__ cur,
                                               u32* __restrict__ rank, int bpp) {
  int p = blockIdx.x / bpp;
  int i = blockIdx.x * 256 + threadIdx.x;
  int o = mo[i];
  rank[i] = offs[(size_t)p * (NPTS + 1) + o] + atomicAdd(&cur[(size_t)p * NPTS + o], 1u);
}

// ---------------- gather-GEMM, natural (k, m-tile) order, rank-scatter rows ----------------
__global__ __launch_bounds__(256) void k_gemm3(const u16* __restrict__ src,
                                               const u16* __restrict__ Wb,
                                               const int* __restrict__ mi,   // pass base
                                               const u32* __restrict__ rank, // pass base
                                               u16* __restrict__ contrib,
                                               int kbase) {
  __shared__ u16 As[64 * LDAB];
  __shared__ u16 Bs[128 * LDAB];
  __shared__ u32 sin[64];
  __shared__ u32 srow[64];
  const int t = threadIdx.x;
  const int b = blockIdx.x;
  const int klocal = b >> 10;
  const int i0 = klocal * MMAP + (b & 1023) * 64;

  if (t < 64) {
    sin[t] = (u32)mi[i0 + t];
    srow[t] = rank[i0 + t];
  }
  const uint4* wsrc = (const uint4*)(Wb + (long)(kbase + klocal) * (CD * CD));
#pragma unroll
  for (int i = 0; i < 8; ++i) {
    int q = i * 256 + t;
    int co = q >> 4, cc = q & 15;
    *(uint4*)&Bs[co * LDAB + cc * 8] = wsrc[q];
  }
  __syncthreads();
#pragma unroll
  for (int i = 0; i < 4; ++i) {
    int q = i * 256 + t;
    int r = q >> 4, cc = q & 15;
    long row = sin[r];
    *(uint4*)&As[r * LDAB + cc * 8] = ((const uint4*)(src + row * CD))[cc];
  }
  __syncthreads();

  const int wave = t >> 6, lane = t & 63;
  const int lr = lane & 15, quad = lane >> 4;
  const int wm = (wave & 1) * 32;
  const int wn = (wave >> 1) * 64;
  f32x4 acc[2][4] = {};
#pragma unroll
  for (int kk = 0; kk < 4; ++kk) {
    bf16x8 a[2], bfr[4];
#pragma unroll
    for (int mt = 0; mt < 2; ++mt)
      a[mt] = *(const bf16x8*)&As[(wm + mt * 16 + lr) * LDAB + (kk * 4 + quad) * 8];
#pragma unroll
    for (int nt = 0; nt < 4; ++nt)
      bfr[nt] = *(const bf16x8*)&Bs[(wn + nt * 16 + lr) * LDAB + (kk * 4 + quad) * 8];
#pragma unroll
    for (int mt = 0; mt < 2; ++mt)
#pragma unroll
      for (int nt = 0; nt < 4; ++nt)
        acc[mt][nt] = __builtin_amdgcn_mfma_f32_16x16x32_bf16(a[mt], bfr[nt], acc[mt][nt], 0, 0, 0);
  }

  // repack C through LDS (C/D layout: col = lane&15, row = quad*4+reg), then coalesced row stores
  __syncthreads();
  u16* Cs = As;  // reuse: 64*132 u16 = 16.9KB <= As 17.4KB
#pragma unroll
  for (int mt = 0; mt < 2; ++mt)
#pragma unroll
    for (int v = 0; v < 4; ++v) {
      int slot = wm + mt * 16 + quad * 4 + v;
#pragma unroll
      for (int nt = 0; nt < 4; ++nt)
        Cs[slot * LDC + wn + nt * 16 + lr] = f2bf(acc[mt][nt][v]);
    }
  __syncthreads();
#pragma unroll
  for (int i = 0; i < 4; ++i) {
    int q = i * 256 + t;
    int r = q >> 4, cc = q & 15;
    size_t rk = srow[r];
    *(uint4*)(contrib + rk * CD + cc * 8) = *(const uint4*)&Cs[r * LDC + cc * 8];
  }
}

// ---------------- segmented reduce v7: group-per-row with 4-deep batched loads ----------------
// 16-lane group owns one row (lane sub -> 8 channels, uint4/entry); the first 4 entry loads are
// issued simultaneously (masked, independent) so the common case (len<=4) is ONE memory
// round-trip. unroll 2 over the 4 assigned rows doubles loads in flight. acc RMW 512B/row
// coalesced; BN stats fused on the last pass (trickled atomics, verified cheap in r0/r1/r4).
__global__ __launch_bounds__(256, 8) void k_segreduce7(const u16* __restrict__ contrib,
                                                       const u32* __restrict__ offs,
                                                       float* __restrict__ acc,
                                                       float* __restrict__ stats,
                                                       int first, int last) {
  const int wave = threadIdx.x >> 6, lane = threadIdx.x & 63;
  const int W = blockIdx.x * 4 + wave;  // 8192 waves, 16 rows each
  const int g = lane >> 4, sub = lane & 15;
  const int r0 = W * 16;
  u32 ld_off = offs[r0 + (lane < 17 ? lane : 16)];
  float sx[8], sq[8];
#pragma unroll
  for (int j = 0; j < 8; ++j) {
    sx[j] = 0.f;
    sq[j] = 0.f;
  }
#pragma unroll 2
  for (int b = 0; b < 4; ++b) {
    const int row = r0 + b * 4 + g;
    const u32 s0 = __shfl(ld_off, b * 4 + g);
    const u32 s1 = __shfl(ld_off, b * 4 + g + 1);
    const int len = (int)(s1 - s0);
    const u32* cp = (const u32*)(contrib + (size_t)s0 * CD) + sub * 4;
    uint4 d0 = {0, 0, 0, 0}, d1 = {0, 0, 0, 0}, d2 = {0, 0, 0, 0}, d3 = {0, 0, 0, 0};
    if (len > 0) d0 = *(const uint4*)(cp);
    if (len > 1) d1 = *(const uint4*)(cp + 64);
    if (len > 2) d2 = *(const uint4*)(cp + 128);
    if (len > 3) d3 = *(const uint4*)(cp + 192);
    float v[8];
    v[0] = (bfLO(d0.x) + bfLO(d1.x)) + (bfLO(d2.x) + bfLO(d3.x));
    v[1] = (bfHI(d0.x) + bfHI(d1.x)) + (bfHI(d2.x) + bfHI(d3.x));
    v[2] = (bfLO(d0.y) + bfLO(d1.y)) + (bfLO(d2.y) + bfLO(d3.y));
    v[3] = (bfHI(d0.y) + bfHI(d1.y)) + (bfHI(d2.y) + bfHI(d3.y));
    v[4] = (bfLO(d0.z) + bfLO(d1.z)) + (bfLO(d2.z) + bfLO(d3.z));
    v[5] = (bfHI(d0.z) + bfHI(d1.z)) + (bfHI(d2.z) + bfHI(d3.z));
    v[6] = (bfLO(d0.w) + bfLO(d1.w)) + (bfLO(d2.w) + bfLO(d3.w));
    v[7] = (bfHI(d0.w) + bfHI(d1.w)) + (bfHI(d2.w) + bfHI(d3.w));
    for (int e = 4; e < len; ++e) {  // rare tail (P(len>4) ~ 18% at kcnt=6)
      uint4 d = *(const uint4*)(cp + (size_t)e * 64);
      v[0] += bfLO(d.x);
      v[1] += bfHI(d.x);
      v[2] += bfLO(d.y);
      v[3] += bfHI(d.y);
      v[4] += bfLO(d.z);
      v[5] += bfHI(d.z);
      v[6] += bfLO(d.w);
      v[7] += bfHI(d.w);
    }
    float4* ap = (float4*)(acc + (size_t)row * CD + sub * 8);
    if (!first) {
      float4 p0 = ap[0], p1 = ap[1];
      v[0] += p0.x;
      v[1] += p0.y;
      v[2] += p0.z;
      v[3] += p0.w;
      v[4] += p1.x;
      v[5] += p1.y;
      v[6] += p1.z;
      v[7] += p1.w;
    }
    ap[0] = make_float4(v[0], v[1], v[2], v[3]);
    ap[1] = make_float4(v[4], v[5], v[6], v[7]);
    if (last) {
#pragma unroll
      for (int j = 0; j < 8; ++j) {
        sx[j] += v[j];
        sq[j] += v[j] * v[j];
      }
    }
  }
  if (last) {
    // combine the 4 groups (same sub -> same channels) then block-reduce via LDS
#pragma unroll
    for (int j = 0; j < 8; ++j) {
      sx[j] += __shfl_xor(sx[j], 16);
      sx[j] += __shfl_xor(sx[j], 32);
      sq[j] += __shfl_xor(sq[j], 16);
      sq[j] += __shfl_xor(sq[j], 32);
    }
    __shared__ float sh[64][16];
    if (lane < 16) {
#pragma unroll
      for (int j = 0; j < 8; ++j) {
        sh[wave * 16 + sub][j] = sx[j];
        sh[wave * 16 + sub][8 + j] = sq[j];
      }
    }
    __syncthreads();
    if (threadIdx.x < 128) {
      int c = threadIdx.x, sb = c >> 3, j = c & 7;
      float a = sh[sb][j] + sh[16 + sb][j] + sh[32 + sb][j] + sh[48 + sb][j];
      float q = sh[sb][8 + j] + sh[16 + sb][8 + j] + sh[32 + sb][8 + j] + sh[48 + sb][8 + j];
      atomicAdd(&stats[c], a);
      atomicAdd(&stats[128 + c], q);
    }
  }
}

// ---------------- BN finalize / apply ----------------
__global__ void k_finalize(const float* __restrict__ stats, const float* __restrict__ gamma,
                           const float* __restrict__ beta, float* __restrict__ scsh) {
  int c = threadIdx.x;
  float mean = stats[c] * (1.f / NPTS);
  float var = stats[128 + c] * (1.f / NPTS) - mean * mean;
  float sc = rsqrtf(var + 1e-5f) * gamma[c];
  scsh[c] = sc;
  scsh[128 + c] = beta[c] - mean * sc;
}

__device__ __forceinline__ float elu(float v) { return v > 0.f ? v : expf(v) - 1.f; }

__global__ __launch_bounds__(256) void k_apply_mid(const float* __restrict__ acc,
                                                   const float* __restrict__ scsh,
                                                   u16* __restrict__ y) {
  long i = ((long)blockIdx.x * 256 + threadIdx.x) * 4;
  int c = (int)(i & 127);
  float4 a = *(const float4*)(acc + i);
  float r0 = elu(a.x * scsh[c] + scsh[128 + c]);
  float r1 = elu(a.y * scsh[c + 1] + scsh[129 + c]);
  float r2 = elu(a.z * scsh[c + 2] + scsh[130 + c]);
  float r3 = elu(a.w * scsh[c + 3] + scsh[131 + c]);
  uint2 v;
  v.x = f2bf(r0) | ((u32)f2bf(r1) << 16);
  v.y = f2bf(r2) | ((u32)f2bf(r3) << 16);
  *(uint2*)(y + i) = v;
}

__global__ __launch_bounds__(256) void k_apply_final(const float* __restrict__ acc,
                                                     const float* __restrict__ scsh,
                                                     const float* __restrict__ x,
                                                     float* __restrict__ out) {
  long i = ((long)blockIdx.x * 256 + threadIdx.x) * 4;
  int c = (int)(i & 127);
  float4 a = *(const float4*)(acc + i);
  float4 rx = *(const float4*)(x + i);
  float4 o;
  o.x = elu(a.x * scsh[c] + scsh[128 + c] + rx.x);
  o.y = elu(a.y * scsh[c + 1] + scsh[129 + c] + rx.y);
  o.z = elu(a.z * scsh[c + 2] + scsh[130 + c] + rx.z);
  o.w = elu(a.w * scsh[c + 3] + scsh[131 + c] + rx.w);
  *(float4*)(out + i) = o;
}

// ---------------- host ----------------
extern "C" void kernel_launch(void* const* d_in, const int* in_sizes, int n_in,
                              void* d_out, int out_size, void* d_ws, size_t ws_size,
                              hipStream_t stream) {
  const float* x = (const float*)d_in[0];
  const float* W1 = (const float*)d_in[1];
  const float* g1 = (const float*)d_in[2];
  const float* b1 = (const float*)d_in[3];
  const float* W2 = (const float*)d_in[4];
  const float* g2 = (const float*)d_in[5];
  const float* b2 = (const float*)d_in[6];
  const int* m1i = (const int*)d_in[7];
  const int* m1o = (const int*)d_in[8];
  const int* m2i = (const int*)d_in[9];
  const int* m2o = (const int*)d_in[10];
  float* out = (float*)d_out;

  char* base = (char*)d_ws;
  size_t off = 0;
  auto alloc = [&](size_t bytes) -> void* {
    void* r = base + off;
    off = (off + bytes + 255) & ~(size_t)255;
    return r;
  };
  // xb doubles as the mid-activation buffer (xb dead after conv1's last gemm pass).
  u16* xb = (u16*)alloc((size_t)NPTS * CD * 2);
  u16* Wb1 = (u16*)alloc((size_t)KOFF * CD * CD * 2);
  u16* Wb2 = (u16*)alloc((size_t)KOFF * CD * CD * 2);
  float* acc = (float*)alloc((size_t)NPTS * CD * 4);
  float* stats = (float*)alloc(256 * 4);
  float* scsh = (float*)alloc(256 * 4);

  // choose kcnt (k-offsets per pass) so contrib + pass-segmented sort buffers fit
  int kcnt = 1, P = KOFF;
  for (int kc = KOFF; kc >= 1; --kc) {
    int Pp = (KOFF + kc - 1) / kc;
    size_t need = off + 2 * (size_t)Pp * NPTS * 4 + 512         // hist+cur
                  + (size_t)Pp * (NPTS + 1) * 4 + 256           // offs
                  + (size_t)Pp * 512 * 4 + 256                  // bsum
                  + (size_t)KOFF * MMAP * 4 + 256               // rank
                  + (size_t)kc * MMAP * CD * 2 + 4096;          // contrib
    if (need <= ws_size) {
      kcnt = kc;
      P = Pp;
      break;
    }
  }
  u32* hist = (u32*)alloc((size_t)P * NPTS * 4);
  u32* cur = (u32*)alloc((size_t)P * NPTS * 4);  // contiguous with hist for one memset
  u32* offs = (u32*)alloc((size_t)P * (NPTS + 1) * 4);
  u32* bsum = (u32*)alloc((size_t)P * 512 * 4);
  u32* rank = (u32*)alloc((size_t)KOFF * MMAP * 4);
  u16* contrib = (u16*)alloc((size_t)kcnt * MMAP * CD * 2);

  k_convert_x<<<(NPTS * CD) / 2048, 256, 0, stream>>>(x, xb);
  k_convert_w<<<(KOFF * 2048 + 255) / 256, 256, 0, stream>>>(W1, Wb1);
  k_convert_w<<<(KOFF * 2048 + 255) / 256, 256, 0, stream>>>(W2, Wb2);

  const int nb = (KOFF * MMAP) / 256;       // hist/rank grid
  const int bpp = kcnt * (MMAP / 256);      // blocks per pass

  auto run_conv = [&](const u16* srcm, const u16* Wbm, const int* mi, const int* mo) {
    hipMemsetAsync(stats, 0, 1024, stream);
    hipMemsetAsync(hist, 0, 2 * (size_t)P * NPTS * 4, stream);
    k_hist2<<<nb, 256, 0, stream>>>(mo, hist, bpp);
    k_scanA2<<<512 * P, 256, 0, stream>>>(hist, offs, bsum);
    k_scanB2<<<P, 512, 0, stream>>>(bsum);
    k_scanC2<<<512 * P, 256, 0, stream>>>(offs, bsum, kcnt);
    k_rank2<<<nb, 256, 0, stream>>>(mo, offs, cur, rank, bpp);
    for (int p = 0; p < P; ++p) {
      int kc = (KOFF - p * kcnt < kcnt) ? KOFF - p * kcnt : kcnt;
      k_gemm3<<<kc * 1024, 256, 0, stream>>>(srcm, Wbm, mi + (long)p * kcnt * MMAP,
                                             rank + (long)p * kcnt * MMAP, contrib, p * kcnt);
      k_segreduce7<<<2048, 256, 0, stream>>>(contrib, offs + (size_t)p * (NPTS + 1), acc, stats,
                                             p == 0 ? 1 : 0, p == P - 1 ? 1 : 0);
    }
  };

  run_conv(xb, Wb1, m1i, m1o);
  k_finalize<<<1, 128, 0, stream>>>(stats, g1, b1, scsh);
  k_apply_mid<<<(NPTS * CD) / 1024, 256, 0, stream>>>(acc, scsh, xb);

  run_conv(xb, Wb2, m2i, m2o);
  k_finalize<<<1, 128, 0, stream>>>(stats, g2, b2, scsh);
  k_apply_final<<<(NPTS * CD) / 1024, 256, 0, stream>>>(acc, scsh, x, out);
}